// Round 2
// baseline (395.015 us; speedup 1.0000x reference)
//
#include <hip/hip_runtime.h>
#include <hip/hip_bf16.h>

#define B_    2
#define C_    64
#define T_    1000
#define NF_   257
#define F_    64
#define H_    128
#define NFP_  288   // padded freq dim: covers start+j <= 256+31 < 288, zero-filled

typedef __bf16  bfv8  __attribute__((ext_vector_type(8)));
typedef float   f32x4 __attribute__((ext_vector_type(4)));
typedef short   s16x8 __attribute__((ext_vector_type(8)));

#define GLOBAL_AS __attribute__((address_space(1)))
#define SHARED_AS __attribute__((address_space(3)))

static __device__ __forceinline__ short f2bf(float f) {
  __hip_bfloat16 h = __float2bfloat16(f);
  return *reinterpret_cast<short*>(&h);
}

static __device__ __forceinline__ void gload_lds16(const void* g, void* l) {
  __builtin_amdgcn_global_load_lds((const GLOBAL_AS void*)g, (SHARED_AS void*)l, 16, 0, 0);
}

// ---------------- x pre-pass: x[b,c,t,k] fp32 -> xT3[b,t,k,c] bf16, k padded to NFP_ with zeros
__global__ __launch_bounds__(256) void xprep_kernel(const float* __restrict__ x,
                                                    short* __restrict__ xT) {
  const int kt = blockIdx.x;               // 0..NFP_/32-1
  const int t  = blockIdx.y;               // 0..T_-1
  const int b  = blockIdx.z;               // 0..B_-1
  const int co = threadIdx.x & 7;          // c octet
  const int k  = kt * 32 + (threadIdx.x >> 3);
  const int c0 = co * 8;
  s16x8 v;
#pragma unroll
  for (int i = 0; i < 8; ++i) {
    float f = 0.0f;
    if (k < NF_) f = x[(((size_t)(b * C_ + c0 + i)) * T_ + t) * NF_ + k];
    v[i] = f2bf(f);
  }
  *reinterpret_cast<s16x8*>(&xT[(((size_t)(b * T_ + t)) * NFP_ + k) * C_ + c0]) = v;
}

// ---------------- W pre-pass: W[f,h,c,j] fp32 -> Wp[f,h,j,c] bf16, j padded to JPAD with zeros
__global__ __launch_bounds__(256) void wprep_kernel(const float* __restrict__ W,
                                                    short* __restrict__ Wp,
                                                    int jmax, int JPAD) {
  const int fh = blockIdx.x;               // f*H_ + h
  const float* Wr = W + (size_t)fh * C_ * jmax;
  short* Or = Wp + (size_t)fh * C_ * JPAD;
  const int KP = C_ * JPAD;
  for (int o = threadIdx.x; o < KP; o += 256) {
    int j = o >> 6, c = o & 63;
    float f = (j < jmax) ? Wr[c * jmax + j] : 0.0f;
    Or[o] = f2bf(f);
  }
}

// ---------------- batched gather-GEMM: per (b,f,ttile): tmp[b,f,t,h] += xT3 gather . Wp
// tile 128(t) x 128(h), BK=64 (= one j slice), 4 waves of 64x64, mfma 16x16x32 bf16
__global__ __launch_bounds__(256) void gemm_kernel(const short* __restrict__ xT,
                                                   const short* __restrict__ Wp,
                                                   const int* __restrict__ idx,
                                                   float* __restrict__ tmp,
                                                   int jmax, int JPAD) {
  __shared__ short As[128 * 64];
  __shared__ short Ws[128 * 64];
  const int tt = blockIdx.x;               // t-tile 0..7
  const int f  = blockIdx.y;
  const int b  = blockIdx.z;
  const int t0 = tt * 128;
  const int tid  = threadIdx.x;
  const int wave = tid >> 6;
  const int lane = tid & 63;
  const int wm = wave >> 1, wn = wave & 1;
  const int start = idx[f * jmax];         // idx[f][0] == starts[f] (no clipping at j=0)
  const int KP = C_ * JPAD;

  f32x4 acc[4][4] = {};

  const int srow = wave * 32 + (lane >> 3);   // staging row base per lane (i adds 8)
  const int scol = (lane & 7) * 8;            // c offset within 64

  for (int j = 0; j < JPAD; ++j) {
    __syncthreads();   // previous compute done before overwrite
    // stage A: 128 rows x 64 c (one j slice), 4 instr/wave
#pragma unroll
    for (int i = 0; i < 4; ++i) {
      int r = srow + i * 8;
      int tc = t0 + r; if (tc >= T_) tc = T_ - 1;   // tail: duplicate row, stores skipped
      const short* src = &xT[(((size_t)(b * T_ + tc)) * NFP_ + (start + j)) * C_ + scol];
      gload_lds16(src, &As[(wave * 32 + i * 8) * 64]);
    }
    // stage W: 128 h-rows x 64 K
#pragma unroll
    for (int i = 0; i < 4; ++i) {
      int h = srow + i * 8;
      const short* src = &Wp[((size_t)(f * H_ + h)) * KP + j * 64 + scol];
      gload_lds16(src, &Ws[(wave * 32 + i * 8) * 64]);
    }
    __syncthreads();   // vmcnt(0) drain + barrier: LDS ready
#pragma unroll
    for (int ks = 0; ks < 2; ++ks) {
      bfv8 a[4], w[4];
#pragma unroll
      for (int mi = 0; mi < 4; ++mi)
        a[mi] = *reinterpret_cast<const bfv8*>(
            &As[(wm * 64 + mi * 16 + (lane & 15)) * 64 + ks * 32 + (lane >> 4) * 8]);
#pragma unroll
      for (int ni = 0; ni < 4; ++ni)
        w[ni] = *reinterpret_cast<const bfv8*>(
            &Ws[(wn * 64 + ni * 16 + (lane & 15)) * 64 + ks * 32 + (lane >> 4) * 8]);
#pragma unroll
      for (int mi = 0; mi < 4; ++mi)
#pragma unroll
        for (int ni = 0; ni < 4; ++ni)
          acc[mi][ni] = __builtin_amdgcn_mfma_f32_16x16x32_bf16(a[mi], w[ni], acc[mi][ni], 0, 0, 0);
    }
  }

  // epilogue: C/D layout col=lane&15 (h), row=(lane>>4)*4+q (t)
  float* obase = tmp + ((size_t)(b * F_ + f)) * T_ * H_;
#pragma unroll
  for (int mi = 0; mi < 4; ++mi) {
#pragma unroll
    for (int q = 0; q < 4; ++q) {
      int t = t0 + wm * 64 + mi * 16 + (lane >> 4) * 4 + q;
      if (t < T_) {
#pragma unroll
        for (int ni = 0; ni < 4; ++ni) {
          int h = wn * 64 + ni * 16 + (lane & 15);
          obase[(size_t)t * H_ + h] = acc[mi][ni][q];
        }
      }
    }
  }
}

// ---------------- final transpose: tmp[b,f,t,h] -> out[b,h,t,f], LDS tiled, coalesced both sides
__global__ __launch_bounds__(256) void trans_kernel(const float* __restrict__ tmp,
                                                    float* __restrict__ out) {
  __shared__ float L[64][129];
  const int t = blockIdx.x;
  const int b = blockIdx.y;
  {
    const int h  = threadIdx.x & 127;
    const int f0 = threadIdx.x >> 7;     // 0..1
#pragma unroll
    for (int i = 0; i < 32; ++i) {
      int fo = f0 * 32 + i;
      L[fo][h] = tmp[(((size_t)(b * F_ + fo)) * T_ + t) * H_ + h];
    }
  }
  __syncthreads();
  {
    const int fo = threadIdx.x & 63;
    const int h0 = threadIdx.x >> 6;     // 0..3
#pragma unroll
    for (int i = 0; i < 32; ++i) {
      int h = h0 * 32 + i;
      out[(((size_t)(b * H_ + h)) * T_ + t) * F_ + fo] = L[fo][h];
    }
  }
}

// ---------------- fallback (exact fp32, slow) if ws too small / unexpected shape
__global__ __launch_bounds__(256) void naive_kernel(const float* __restrict__ x,
                                                    const float* __restrict__ W,
                                                    const int* __restrict__ idx,
                                                    float* __restrict__ out,
                                                    int jmax, size_t n) {
  size_t o = (size_t)blockIdx.x * 256 + threadIdx.x;
  if (o >= n) return;
  int f = (int)(o & 63);
  size_t r = o >> 6;
  int t = (int)(r % T_); r /= T_;
  int h = (int)(r % H_);
  int b = (int)(r / H_);
  float s = 0.0f;
  for (int c = 0; c < C_; ++c) {
    const float* xr = x + (((size_t)(b * C_ + c)) * T_ + t) * NF_;
    const float* wr = W + (((size_t)(f * H_ + h)) * C_ + c) * jmax;
    for (int j = 0; j < jmax; ++j) s += xr[idx[f * jmax + j]] * wr[j];
  }
  out[o] = s;
}

extern "C" void kernel_launch(void* const* d_in, const int* in_sizes, int n_in,
                              void* d_out, int out_size, void* d_ws, size_t ws_size,
                              hipStream_t stream) {
  const float* x  = (const float*)d_in[0];
  const float* W  = (const float*)d_in[1];
  const int* idx  = (const int*)d_in[2];
  float* out      = (float*)d_out;

  const int jmax = in_sizes[2] / F_;          // idx is (F_, jmax)
  const int JPAD = (jmax + 7) & ~7;

  const size_t xbytes = (size_t)B_ * T_ * NFP_ * C_ * 2;
  const size_t wbytes = (size_t)F_ * H_ * C_ * JPAD * 2;
  const size_t tbytes = (size_t)B_ * F_ * T_ * H_ * 4;

  if (JPAD <= 32 && ws_size >= xbytes + wbytes + tbytes) {
    short* xT  = (short*)d_ws;
    short* Wp  = (short*)((char*)d_ws + xbytes);
    float* tmp = (float*)((char*)d_ws + xbytes + wbytes);

    hipLaunchKernelGGL(xprep_kernel, dim3(NFP_ / 32, T_, B_), dim3(256), 0, stream, x, xT);
    hipLaunchKernelGGL(wprep_kernel, dim3(F_ * H_), dim3(256), 0, stream, W, Wp, jmax, JPAD);
    hipLaunchKernelGGL(gemm_kernel, dim3((T_ + 127) / 128, F_, B_), dim3(256), 0, stream,
                       xT, Wp, idx, tmp, jmax, JPAD);
    hipLaunchKernelGGL(trans_kernel, dim3(T_, B_), dim3(256), 0, stream, tmp, out);
  } else {
    const size_t n = (size_t)B_ * H_ * T_ * F_;
    hipLaunchKernelGGL(naive_kernel, dim3((unsigned)((n + 255) / 256)), dim3(256), 0, stream,
                       x, W, idx, out, jmax, n);
  }
}

// Round 3
// 352.537 us; speedup vs baseline: 1.1205x; 1.1205x over previous
//
#include <hip/hip_runtime.h>
#include <hip/hip_bf16.h>

#define B_    2
#define C_    64
#define T_    1000
#define NF_   257
#define F_    64
#define H_    128
#define NFP_  288   // padded freq dim (rows zero-filled for k>=NF_)

typedef __bf16  bfv8  __attribute__((ext_vector_type(8)));
typedef float   f32x4 __attribute__((ext_vector_type(4)));
typedef short   s16x8 __attribute__((ext_vector_type(8)));

#define GLOBAL_AS __attribute__((address_space(1)))
#define SHARED_AS __attribute__((address_space(3)))

static __device__ __forceinline__ short f2bf(float f) {
  __hip_bfloat16 h = __float2bfloat16(f);
  return *reinterpret_cast<short*>(&h);
}

static __device__ __forceinline__ void gload_lds16(const void* g, void* l) {
  __builtin_amdgcn_global_load_lds((const GLOBAL_AS void*)g, (SHARED_AS void*)l, 16, 0, 0);
}

// ---------------- x pre-pass: x[b,c,t,k] fp32 -> xT[b,t,k,c] bf16 (k zero-filled to NFP_)
// LDS-tiled transpose: reads coalesced along k, writes coalesced along c.
__global__ __launch_bounds__(256) void xprep_kernel(const float* __restrict__ x,
                                                    short* __restrict__ xT) {
  __shared__ float Ls[64][33];          // [c][k], +1 pad: all accesses <=2-way banked
  const int k0 = blockIdx.x * 32;       // 0..8 -> k tiles of 32
  const int t  = blockIdx.y;
  const int b  = blockIdx.z;
  {
    const int k  = threadIdx.x & 31;    // lanes along k: 128B contiguous reads
    const int cb = threadIdx.x >> 5;    // 0..7
#pragma unroll
    for (int i = 0; i < 8; ++i) {
      int c = cb + 8 * i;
      float f = 0.0f;
      int kk = k0 + k;
      if (kk < NF_) f = x[(((size_t)(b * C_ + c)) * T_ + t) * NF_ + kk];
      Ls[c][k] = f;
    }
  }
  __syncthreads();
  {
    const int k  = threadIdx.x >> 3;         // 0..31
    const int c0 = (threadIdx.x & 7) * 8;    // lanes along c: 128B contiguous writes
    s16x8 v;
#pragma unroll
    for (int i = 0; i < 8; ++i) v[i] = f2bf(Ls[c0 + i][k]);
    *reinterpret_cast<s16x8*>(&xT[(((size_t)(b * T_ + t)) * NFP_ + k0 + k) * C_ + c0]) = v;
  }
}

// ---------------- W pre-pass: W[f,h,c,j] fp32 -> Wp[f,h,j,c] bf16 (j padded to JPAD)
// Also detects per-filter width (last j with any nonzero W) -> wwidth[f].
// Block = (f, 8 h-rows): reads fully contiguous, writes 16B vectors.
__global__ __launch_bounds__(256) void wprep_kernel(const float* __restrict__ W,
                                                    short* __restrict__ Wp,
                                                    int* __restrict__ wwidth,
                                                    int jmax, int JPAD) {
  extern __shared__ short Lw[];          // [8][C_*jmax]
  __shared__ int smax;
  const int f  = blockIdx.x >> 4;
  const int h8 = (blockIdx.x & 15) * 8;
  const int tid = threadIdx.x;
  if (tid == 0) smax = 0;
  __syncthreads();
  const int chunk = 8 * C_ * jmax;      // contiguous floats for 8 h rows
  const float* src = W + ((size_t)(f * H_ + h8)) * C_ * jmax;
  int lm = -1;
  for (int o = tid; o < chunk; o += 256) {
    float v = src[o];
    Lw[o] = f2bf(v);
    if (v != 0.0f) { int j = o % jmax; if (j > lm) lm = j; }
  }
  atomicMax(&smax, lm + 1);
  __syncthreads();
  if (tid == 0) atomicMax(&wwidth[f], smax);
  // write transposed: (h, j, c) with c fastest, 16B per store
  const int KP = C_ * JPAD;
  const int nv = 8 * JPAD * 8;          // s16x8 stores for this chunk
  for (int id = tid; id < nv; id += 256) {
    int c0 = (id & 7) * 8;
    int j  = (id >> 3) % JPAD;
    int h  = (id >> 3) / JPAD;
    s16x8 v;
    if (j < jmax) {
#pragma unroll
      for (int u = 0; u < 8; ++u) v[u] = Lw[h * C_ * jmax + (c0 + u) * jmax + j];
    } else {
      short z = f2bf(0.0f);
#pragma unroll
      for (int u = 0; u < 8; ++u) v[u] = z;
    }
    *reinterpret_cast<s16x8*>(&Wp[((size_t)(f * H_ + h8 + h)) * KP + j * C_ + c0]) = v;
  }
}

// ---------------- batched gather-GEMM: per (b,f,ttile): tmp[b,f,t,h] = xT gather . Wp
// tile 128(t) x 128(h), BK=64 (one j slice), 4 waves of 64x64, mfma 16x16x32 bf16.
// K-loop truncated to per-filter width. 1D grid + bijective XCD swizzle (f fastest
// within each XCD chunk -> balanced widths per XCD, x-tile L2 locality).
__global__ __launch_bounds__(256) void gemm_kernel(const short* __restrict__ xT,
                                                   const short* __restrict__ Wp,
                                                   const int* __restrict__ idx,
                                                   const int* __restrict__ wwidth,
                                                   float* __restrict__ tmp,
                                                   int jmax, int JPAD) {
  __shared__ short As[128 * 64];
  __shared__ short Ws[128 * 64];
  const int id = blockIdx.x;                 // 0..1023
  const int sw = (id & 7) * 128 + (id >> 3); // bijective: 1024 % 8 == 0
  const int f  = sw & 63;
  const int tb = sw >> 6;
  const int tt = tb & 7;
  const int b  = tb >> 3;
  const int t0 = tt * 128;
  const int tid  = threadIdx.x;
  const int wave = tid >> 6;
  const int lane = tid & 63;
  const int wm = wave >> 1, wn = wave & 1;
  const int start = idx[f * jmax];           // starts[f] (no clipping at j=0)
  const int KP = C_ * JPAD;
  int wf = wwidth[f];
  if (wf > JPAD) wf = JPAD;

  f32x4 acc[4][4] = {};

  const int srow = wave * 32 + (lane >> 3);
  const int scol = (lane & 7) * 8;

  for (int j = 0; j < wf; ++j) {
    __syncthreads();
#pragma unroll
    for (int i = 0; i < 4; ++i) {
      int r = srow + i * 8;
      int tc = t0 + r; if (tc >= T_) tc = T_ - 1;
      const short* src = &xT[(((size_t)(b * T_ + tc)) * NFP_ + (start + j)) * C_ + scol];
      gload_lds16(src, &As[(wave * 32 + i * 8) * 64]);
    }
#pragma unroll
    for (int i = 0; i < 4; ++i) {
      int h = srow + i * 8;
      const short* src = &Wp[((size_t)(f * H_ + h)) * KP + j * 64 + scol];
      gload_lds16(src, &Ws[(wave * 32 + i * 8) * 64]);
    }
    __syncthreads();
#pragma unroll
    for (int ks = 0; ks < 2; ++ks) {
      bfv8 a[4], w[4];
#pragma unroll
      for (int mi = 0; mi < 4; ++mi)
        a[mi] = *reinterpret_cast<const bfv8*>(
            &As[(wm * 64 + mi * 16 + (lane & 15)) * 64 + ks * 32 + (lane >> 4) * 8]);
#pragma unroll
      for (int ni = 0; ni < 4; ++ni)
        w[ni] = *reinterpret_cast<const bfv8*>(
            &Ws[(wn * 64 + ni * 16 + (lane & 15)) * 64 + ks * 32 + (lane >> 4) * 8]);
#pragma unroll
      for (int mi = 0; mi < 4; ++mi)
#pragma unroll
        for (int ni = 0; ni < 4; ++ni)
          acc[mi][ni] = __builtin_amdgcn_mfma_f32_16x16x32_bf16(a[mi], w[ni], acc[mi][ni], 0, 0, 0);
    }
  }

  // epilogue: C/D layout col=lane&15 (h), row=(lane>>4)*4+q (t)
  float* obase = tmp + ((size_t)(b * F_ + f)) * T_ * H_;
#pragma unroll
  for (int mi = 0; mi < 4; ++mi) {
#pragma unroll
    for (int q = 0; q < 4; ++q) {
      int t = t0 + wm * 64 + mi * 16 + (lane >> 4) * 4 + q;
      if (t < T_) {
#pragma unroll
        for (int ni = 0; ni < 4; ++ni) {
          int h = wn * 64 + ni * 16 + (lane & 15);
          obase[(size_t)t * H_ + h] = acc[mi][ni][q];
        }
      }
    }
  }
}

// ---------------- final transpose: tmp[b,f,t,h] -> out[b,h,t,f], LDS tiled
__global__ __launch_bounds__(256) void trans_kernel(const float* __restrict__ tmp,
                                                    float* __restrict__ out) {
  __shared__ float L[64][129];
  const int t = blockIdx.x;
  const int b = blockIdx.y;
  {
    const int h  = threadIdx.x & 127;
    const int f0 = threadIdx.x >> 7;
#pragma unroll
    for (int i = 0; i < 32; ++i) {
      int fo = f0 * 32 + i;
      L[fo][h] = tmp[(((size_t)(b * F_ + fo)) * T_ + t) * H_ + h];
    }
  }
  __syncthreads();
  {
    const int fo = threadIdx.x & 63;
    const int h0 = threadIdx.x >> 6;
#pragma unroll
    for (int i = 0; i < 32; ++i) {
      int h = h0 * 32 + i;
      out[(((size_t)(b * H_ + h)) * T_ + t) * F_ + fo] = L[fo][h];
    }
  }
}

// ---------------- fallback (exact fp32, slow)
__global__ __launch_bounds__(256) void naive_kernel(const float* __restrict__ x,
                                                    const float* __restrict__ W,
                                                    const int* __restrict__ idx,
                                                    float* __restrict__ out,
                                                    int jmax, size_t n) {
  size_t o = (size_t)blockIdx.x * 256 + threadIdx.x;
  if (o >= n) return;
  int f = (int)(o & 63);
  size_t r = o >> 6;
  int t = (int)(r % T_); r /= T_;
  int h = (int)(r % H_);
  int b = (int)(r / H_);
  float s = 0.0f;
  for (int c = 0; c < C_; ++c) {
    const float* xr = x + (((size_t)(b * C_ + c)) * T_ + t) * NF_;
    const float* wr = W + (((size_t)(f * H_ + h)) * C_ + c) * jmax;
    for (int j = 0; j < jmax; ++j) s += xr[idx[f * jmax + j]] * wr[j];
  }
  out[o] = s;
}

extern "C" void kernel_launch(void* const* d_in, const int* in_sizes, int n_in,
                              void* d_out, int out_size, void* d_ws, size_t ws_size,
                              hipStream_t stream) {
  const float* x  = (const float*)d_in[0];
  const float* W  = (const float*)d_in[1];
  const int* idx  = (const int*)d_in[2];
  float* out      = (float*)d_out;

  const int jmax = in_sizes[2] / F_;          // idx is (F_, jmax)
  const int JPAD = (jmax + 7) & ~7;

  const size_t xbytes = (size_t)B_ * T_ * NFP_ * C_ * 2;
  const size_t wbytes = (size_t)F_ * H_ * C_ * JPAD * 2;
  const size_t tbytes = (size_t)B_ * F_ * T_ * H_ * 4;
  const size_t wwbytes = 256;                 // wwidth[64] (+pad)
  const size_t lws = (size_t)8 * C_ * jmax * 2;   // wprep dynamic LDS

  if (JPAD <= 32 && ws_size >= xbytes + wbytes + tbytes + wwbytes && lws <= 48 * 1024) {
    short* xT   = (short*)d_ws;
    short* Wp   = (short*)((char*)d_ws + xbytes);
    float* tmp  = (float*)((char*)d_ws + xbytes + wbytes);
    int* wwidth = (int*)((char*)d_ws + xbytes + wbytes + tbytes);
    // NOTE: wwidth is re-poisoned to 0xAAAAAAAA (negative int) before each call;
    // wprep's atomicMax(wwidth[f], width>=0) therefore self-initializes it.

    hipLaunchKernelGGL(xprep_kernel, dim3(NFP_ / 32, T_, B_), dim3(256), 0, stream, x, xT);
    hipLaunchKernelGGL(wprep_kernel, dim3(F_ * 16), dim3(256), lws, stream,
                       W, Wp, wwidth, jmax, JPAD);
    hipLaunchKernelGGL(gemm_kernel, dim3(1024), dim3(256), 0, stream,
                       xT, Wp, idx, wwidth, tmp, jmax, JPAD);
    hipLaunchKernelGGL(trans_kernel, dim3(T_, B_), dim3(256), 0, stream, tmp, out);
  } else {
    const size_t n = (size_t)B_ * H_ * T_ * F_;
    hipLaunchKernelGGL(naive_kernel, dim3((unsigned)((n + 255) / 256)), dim3(256), 0, stream,
                       x, W, idx, out, jmax, n);
  }
}

// Round 4
// 339.537 us; speedup vs baseline: 1.1634x; 1.0383x over previous
//
#include <hip/hip_runtime.h>
#include <hip/hip_bf16.h>

#define B_    2
#define C_    64
#define T_    1000
#define NF_   257
#define F_    64
#define H_    128
#define NFP_  288   // padded freq dim (rows zero-filled for k>=NF_)

typedef __bf16  bfv8  __attribute__((ext_vector_type(8)));
typedef float   f32x4 __attribute__((ext_vector_type(4)));
typedef short   s16x8 __attribute__((ext_vector_type(8)));

#define GLOBAL_AS __attribute__((address_space(1)))
#define SHARED_AS __attribute__((address_space(3)))

static __device__ __forceinline__ short f2bf(float f) {
  __hip_bfloat16 h = __float2bfloat16(f);
  return *reinterpret_cast<short*>(&h);
}
static __device__ __forceinline__ float bf2f(short s) {
  __hip_bfloat16 h = *reinterpret_cast<__hip_bfloat16*>(&s);
  return __bfloat162float(h);
}

static __device__ __forceinline__ void gload_lds16(const void* g, void* l) {
  __builtin_amdgcn_global_load_lds((const GLOBAL_AS void*)g, (SHARED_AS void*)l, 16, 0, 0);
}

// ---------------- x pre-pass: x[b,c,t,k] fp32 -> xT[b,t,k,c] bf16 (k zero-filled to NFP_)
__global__ __launch_bounds__(256) void xprep_kernel(const float* __restrict__ x,
                                                    short* __restrict__ xT) {
  __shared__ float Ls[64][33];
  const int k0 = blockIdx.x * 32;
  const int t  = blockIdx.y;
  const int b  = blockIdx.z;
  {
    const int k  = threadIdx.x & 31;
    const int cb = threadIdx.x >> 5;
#pragma unroll
    for (int i = 0; i < 8; ++i) {
      int c = cb + 8 * i;
      float f = 0.0f;
      int kk = k0 + k;
      if (kk < NF_) f = x[(((size_t)(b * C_ + c)) * T_ + t) * NF_ + kk];
      Ls[c][k] = f;
    }
  }
  __syncthreads();
  {
    const int k  = threadIdx.x >> 3;
    const int c0 = (threadIdx.x & 7) * 8;
    s16x8 v;
#pragma unroll
    for (int i = 0; i < 8; ++i) v[i] = f2bf(Ls[c0 + i][k]);
    *reinterpret_cast<s16x8*>(&xT[(((size_t)(b * T_ + t)) * NFP_ + k0 + k) * C_ + c0]) = v;
  }
}

// ---------------- W pre-pass: W[f,h,c,j] fp32 -> Wp[f,h,j,c] bf16 (j padded), width detect
__global__ __launch_bounds__(256) void wprep_kernel(const float* __restrict__ W,
                                                    short* __restrict__ Wp,
                                                    int* __restrict__ wwidth,
                                                    int jmax, int JPAD) {
  extern __shared__ short Lw[];
  __shared__ int smax;
  const int f  = blockIdx.x >> 4;
  const int h8 = (blockIdx.x & 15) * 8;
  const int tid = threadIdx.x;
  if (tid == 0) smax = 0;
  __syncthreads();
  const int chunk = 8 * C_ * jmax;
  const float* src = W + ((size_t)(f * H_ + h8)) * C_ * jmax;
  int lm = -1;
  for (int o = tid; o < chunk; o += 256) {
    float v = src[o];
    Lw[o] = f2bf(v);
    if (v != 0.0f) { int j = o % jmax; if (j > lm) lm = j; }
  }
  atomicMax(&smax, lm + 1);
  __syncthreads();
  if (tid == 0) atomicMax(&wwidth[f], smax);
  const int KP = C_ * JPAD;
  const int nv = 8 * JPAD * 8;
  for (int id = tid; id < nv; id += 256) {
    int c0 = (id & 7) * 8;
    int j  = (id >> 3) % JPAD;
    int h  = (id >> 3) / JPAD;
    s16x8 v;
    if (j < jmax) {
#pragma unroll
      for (int u = 0; u < 8; ++u) v[u] = Lw[h * C_ * jmax + (c0 + u) * jmax + j];
    } else {
      short z = f2bf(0.0f);
#pragma unroll
      for (int u = 0; u < 8; ++u) v[u] = z;
    }
    *reinterpret_cast<s16x8*>(&Wp[((size_t)(f * H_ + h8 + h)) * KP + j * C_ + c0]) = v;
  }
}

// ---------------- batched gather-GEMM, 2-deep dbuf pipeline + counted vmcnt + XOR swizzle
// tile 128(t) x 128(h), BK=64 (one j slice), 4 waves of 64x64, mfma 16x16x32 bf16
__global__ __launch_bounds__(256) void gemm_kernel(const short* __restrict__ xT,
                                                   const short* __restrict__ Wp,
                                                   const int* __restrict__ idx,
                                                   const int* __restrict__ wwidth,
                                                   short* __restrict__ tmp,
                                                   int jmax, int JPAD) {
  __shared__ short As[2][128 * 64];
  __shared__ short Ws[2][128 * 64];
  const int id = blockIdx.x;                 // 0..1023
  const int sw = (id & 7) * 128 + (id >> 3); // bijective XCD swizzle (1024%8==0)
  const int f  = sw & 63;
  const int tb = sw >> 6;
  const int tt = tb & 7;
  const int b  = tb >> 3;
  const int t0 = tt * 128;
  const int tid  = threadIdx.x;
  const int wave = tid >> 6;
  const int lane = tid & 63;
  const int wm = wave >> 1, wn = wave & 1;
  const int start = idx[f * jmax];
  const int KP = C_ * JPAD;
  int wf = wwidth[f];
  if (wf > JPAD) wf = JPAD;

  // staging geometry: lane -> row (lane>>3) within 8-row group, swizzled source slot
  const int lrow = lane >> 3;                     // == absolute_row & 7
  const int lsw  = ((lane & 7) ^ lrow) * 8;       // pre-swizzled global col (shorts)
  const int l7   = lane & 7;                      // == read row & 7

  f32x4 acc[4][4] = {};

#define STAGE(J, BSEL)                                                              \
  {                                                                                 \
    _Pragma("unroll")                                                               \
    for (int i = 0; i < 4; ++i) {                                                   \
      int tc = t0 + wave * 32 + i * 8 + lrow; if (tc >= T_) tc = T_ - 1;            \
      gload_lds16(&xT[(((size_t)(b * T_ + tc)) * NFP_ + (start + (J))) * C_ + lsw], \
                  &As[BSEL][(wave * 32 + i * 8) * 64]);                             \
    }                                                                               \
    _Pragma("unroll")                                                               \
    for (int i = 0; i < 4; ++i) {                                                   \
      int h = wave * 32 + i * 8 + lrow;                                             \
      gload_lds16(&Wp[((size_t)(f * H_ + h)) * KP + (J) * 64 + lsw],                \
                  &Ws[BSEL][(wave * 32 + i * 8) * 64]);                             \
    }                                                                               \
  }

  if (wf > 0) STAGE(0, 0);
  if (wf > 1) STAGE(1, 1);
  asm volatile("" ::: "memory");
  __builtin_amdgcn_sched_barrier(0);

  for (int j = 0; j < wf; ++j) {
    const int cur = j & 1;
    // wait for stage j (8 loads of stage j+1 may stay in flight)
    if (j + 1 < wf) asm volatile("s_waitcnt vmcnt(8)" ::: "memory");
    else            asm volatile("s_waitcnt vmcnt(0)" ::: "memory");
    __builtin_amdgcn_sched_barrier(0);
    asm volatile("s_barrier" ::: "memory");
    __builtin_amdgcn_sched_barrier(0);

#pragma unroll
    for (int ks = 0; ks < 2; ++ks) {
      bfv8 a[4], w[4];
#pragma unroll
      for (int mi = 0; mi < 4; ++mi) {
        int rA = wm * 64 + mi * 16 + (lane & 15);          // rA&7 == l7
        int sA = ((ks * 4 + (lane >> 4)) ^ l7) * 8;        // swizzled read slot
        a[mi] = *reinterpret_cast<const bfv8*>(&As[cur][rA * 64 + sA]);
      }
#pragma unroll
      for (int ni = 0; ni < 4; ++ni) {
        int rB = wn * 64 + ni * 16 + (lane & 15);
        int sB = ((ks * 4 + (lane >> 4)) ^ l7) * 8;
        w[ni] = *reinterpret_cast<const bfv8*>(&Ws[cur][rB * 64 + sB]);
      }
#pragma unroll
      for (int mi = 0; mi < 4; ++mi)
#pragma unroll
        for (int ni = 0; ni < 4; ++ni)
          acc[mi][ni] = __builtin_amdgcn_mfma_f32_16x16x32_bf16(a[mi], w[ni], acc[mi][ni], 0, 0, 0);
    }

    __builtin_amdgcn_sched_barrier(0);
    asm volatile("s_barrier" ::: "memory");   // all waves done reading buf[cur]
    __builtin_amdgcn_sched_barrier(0);
    if (j + 2 < wf) STAGE(j + 2, cur);        // overwrite cur for j+2
    asm volatile("" ::: "memory");
  }
#undef STAGE

  // epilogue: C/D layout col=lane&15 (h), row=(lane>>4)*4+q (t); store bf16
  short* obase = tmp + ((size_t)(b * F_ + f)) * T_ * H_;
#pragma unroll
  for (int mi = 0; mi < 4; ++mi) {
#pragma unroll
    for (int q = 0; q < 4; ++q) {
      int t = t0 + wm * 64 + mi * 16 + (lane >> 4) * 4 + q;
      if (t < T_) {
#pragma unroll
        for (int ni = 0; ni < 4; ++ni) {
          int h = wn * 64 + ni * 16 + (lane & 15);
          obase[(size_t)t * H_ + h] = f2bf(acc[mi][ni][q]);
        }
      }
    }
  }
}

// ---------------- final transpose: tmp[b,f,t,h] bf16 -> out[b,h,t,f] fp32
__global__ __launch_bounds__(256) void trans_kernel(const short* __restrict__ tmp,
                                                    float* __restrict__ out) {
  __shared__ float L[64][129];
  const int t = blockIdx.x;
  const int b = blockIdx.y;
  {
    const int h0 = (threadIdx.x & 15) * 8;
    const int fb = threadIdx.x >> 4;     // 0..15
#pragma unroll
    for (int i = 0; i < 4; ++i) {
      int f = fb + 16 * i;
      s16x8 v = *reinterpret_cast<const s16x8*>(
          &tmp[(((size_t)(b * F_ + f)) * T_ + t) * H_ + h0]);
#pragma unroll
      for (int u = 0; u < 8; ++u) L[f][h0 + u] = bf2f(v[u]);
    }
  }
  __syncthreads();
  {
    const int fo = threadIdx.x & 63;
    const int h0 = threadIdx.x >> 6;
#pragma unroll
    for (int i = 0; i < 32; ++i) {
      int h = h0 * 32 + i;
      out[(((size_t)(b * H_ + h)) * T_ + t) * F_ + fo] = L[fo][h];
    }
  }
}

// ---------------- fallback (exact fp32, slow)
__global__ __launch_bounds__(256) void naive_kernel(const float* __restrict__ x,
                                                    const float* __restrict__ W,
                                                    const int* __restrict__ idx,
                                                    float* __restrict__ out,
                                                    int jmax, size_t n) {
  size_t o = (size_t)blockIdx.x * 256 + threadIdx.x;
  if (o >= n) return;
  int f = (int)(o & 63);
  size_t r = o >> 6;
  int t = (int)(r % T_); r /= T_;
  int h = (int)(r % H_);
  int b = (int)(r / H_);
  float s = 0.0f;
  for (int c = 0; c < C_; ++c) {
    const float* xr = x + (((size_t)(b * C_ + c)) * T_ + t) * NF_;
    const float* wr = W + (((size_t)(f * H_ + h)) * C_ + c) * jmax;
    for (int j = 0; j < jmax; ++j) s += xr[idx[f * jmax + j]] * wr[j];
  }
  out[o] = s;
}

extern "C" void kernel_launch(void* const* d_in, const int* in_sizes, int n_in,
                              void* d_out, int out_size, void* d_ws, size_t ws_size,
                              hipStream_t stream) {
  const float* x  = (const float*)d_in[0];
  const float* W  = (const float*)d_in[1];
  const int* idx  = (const int*)d_in[2];
  float* out      = (float*)d_out;

  const int jmax = in_sizes[2] / F_;          // idx is (F_, jmax)
  const int JPAD = (jmax + 7) & ~7;

  const size_t xbytes = (size_t)B_ * T_ * NFP_ * C_ * 2;
  const size_t wbytes = (size_t)F_ * H_ * C_ * JPAD * 2;
  const size_t tbytes = (size_t)B_ * F_ * T_ * H_ * 2;   // bf16 tmp
  const size_t wwbytes = 256;
  const size_t lws = (size_t)8 * C_ * jmax * 2;

  if (JPAD <= 32 && ws_size >= xbytes + wbytes + tbytes + wwbytes && lws <= 48 * 1024) {
    short* xT   = (short*)d_ws;
    short* Wp   = (short*)((char*)d_ws + xbytes);
    short* tmp  = (short*)((char*)d_ws + xbytes + wbytes);
    int* wwidth = (int*)((char*)d_ws + xbytes + wbytes + tbytes);
    // wwidth is re-poisoned to 0xAAAAAAAA (negative) each call; wprep's
    // atomicMax(wwidth[f], width>=0) self-initializes it.

    hipLaunchKernelGGL(xprep_kernel, dim3(NFP_ / 32, T_, B_), dim3(256), 0, stream, x, xT);
    hipLaunchKernelGGL(wprep_kernel, dim3(F_ * 16), dim3(256), lws, stream,
                       W, Wp, wwidth, jmax, JPAD);
    hipLaunchKernelGGL(gemm_kernel, dim3(1024), dim3(256), 0, stream,
                       xT, Wp, idx, wwidth, tmp, jmax, JPAD);
    hipLaunchKernelGGL(trans_kernel, dim3(T_, B_), dim3(256), 0, stream, tmp, out);
  } else {
    const size_t n = (size_t)B_ * H_ * T_ * F_;
    hipLaunchKernelGGL(naive_kernel, dim3((unsigned)((n + 255) / 256)), dim3(256), 0, stream,
                       x, W, idx, out, jmax, n);
  }
}